// Round 3
// baseline (794.631 us; speedup 1.0000x reference)
//
#include <hip/hip_runtime.h>
#include <hip/hip_bf16.h>

typedef __bf16 bf16x8 __attribute__((ext_vector_type(8)));
typedef __bf16 bf16x4 __attribute__((ext_vector_type(4)));
typedef float f32x4 __attribute__((ext_vector_type(4)));

#define S_LEN 2048
#define HID 2560
#define NH 32
#define NKV 8
#define HD 128
#define QSZ 4096      // NH*HD
#define KVSZ 1024     // NKV*HD
#define QKV_N 6144    // QSZ + 2*KVSZ
#define SCALE_Q 0.08838834764831845f  // 128^-0.5
#define LOG2_THETA 13.287712379549449f // log2(10000)

// ---------------- f32 -> bf16 cast ----------------
__global__ void castk(const float* __restrict__ in, __bf16* __restrict__ out, int n4) {
  int i = blockIdx.x * blockDim.x + threadIdx.x;
  int stride = gridDim.x * blockDim.x;
  for (; i < n4; i += stride) {
    float4 v = ((const float4*)in)[i];
    bf16x4 o;
    o[0] = (__bf16)v.x; o[1] = (__bf16)v.y; o[2] = (__bf16)v.z; o[3] = (__bf16)v.w;
    ((bf16x4*)out)[i] = o;
  }
}

// ---------------- async global->LDS helper ----------------
__device__ __forceinline__ void gload16(const void* g, void* l) {
  __builtin_amdgcn_global_load_lds((const __attribute__((address_space(1))) void*)g,
                                   (__attribute__((address_space(3))) void*)l, 16, 0, 0);
}

// ---------------- bf16 GEMM: C[M][N] = A[M][K] * B[N][K]^T, fp32 out ----------------
// m97 structure: 128x128 tile, BK=32, global_load_lds(16), 4 waves 2x2, 16 MFMA/K-step.
__global__ __launch_bounds__(256, 2) void gemm_bt(
    const __bf16* __restrict__ A, const __bf16* __restrict__ B, float* __restrict__ C,
    int M, int N, int K) {
  __shared__ __attribute__((aligned(16))) __bf16 lta[128 * 32];
  __shared__ __attribute__((aligned(16))) __bf16 ltb[128 * 32];
  const int t = threadIdx.x, w = t >> 6, l = t & 63;
  const int bn = blockIdx.x, bm = blockIdx.y;
  const int wr = w >> 1, wc = w & 1;
  const int lg = l >> 4, li = l & 15;

  f32x4 acc[4][4];
#pragma unroll
  for (int i = 0; i < 4; ++i)
#pragma unroll
    for (int j = 0; j < 4; ++j) acc[i][j] = (f32x4){0.f, 0.f, 0.f, 0.f};

  const int nkt = K >> 5;
  const int c0 = w * 2, c1 = w * 2 + 1;
  const int row0 = c0 * 16 + (l >> 2), row1 = c1 * 16 + (l >> 2);
  const int cole = (l & 3) * 8;
  const __bf16* ga = A + (size_t)(bm * 128) * K + cole;
  const __bf16* gb = B + (size_t)(bn * 128) * K + cole;

  for (int kt = 0; kt < nkt; ++kt) {
    const size_t ko = (size_t)kt * 32;
    gload16(ga + (size_t)row0 * K + ko, &lta[c0 * 512]);
    gload16(gb + (size_t)row0 * K + ko, &ltb[c0 * 512]);
    gload16(ga + (size_t)row1 * K + ko, &lta[c1 * 512]);
    gload16(gb + (size_t)row1 * K + ko, &ltb[c1 * 512]);
    __syncthreads();
    bf16x8 af[4], bfr[4];
#pragma unroll
    for (int f = 0; f < 4; ++f) {
      af[f]  = *(const bf16x8*)&lta[(wr * 64 + f * 16 + li) * 32 + lg * 8];
      bfr[f] = *(const bf16x8*)&ltb[(wc * 64 + f * 16 + li) * 32 + lg * 8];
    }
#pragma unroll
    for (int fm = 0; fm < 4; ++fm)
#pragma unroll
      for (int fn = 0; fn < 4; ++fn)
        acc[fm][fn] = __builtin_amdgcn_mfma_f32_16x16x32_bf16(af[fm], bfr[fn], acc[fm][fn], 0, 0, 0);
    __syncthreads();
  }

  float* cp = C + (size_t)(bm * 128 + wr * 64 + lg * 4) * N + bn * 128 + wc * 64 + li;
#pragma unroll
  for (int fm = 0; fm < 4; ++fm)
#pragma unroll
    for (int fn = 0; fn < 4; ++fn)
#pragma unroll
      for (int r = 0; r < 4; ++r)
        cp[(size_t)(fm * 16 + r) * N + fn * 16] = acc[fm][fn][r];
}

// ---------------- fused RMSNorm + RoPE, write bf16 q/k ----------------
__global__ __launch_bounds__(64) void norm_rope(
    const float* __restrict__ qkv, const int* __restrict__ positions,
    const float* __restrict__ qw, const float* __restrict__ kw,
    __bf16* __restrict__ q_bf, __bf16* __restrict__ k_bf) {
  const int s = blockIdx.x, hh = blockIdx.y, l = threadIdx.x;
  const float* row;
  const float* wgt;
  __bf16* outp;
  float scale;
  if (hh < NH) {
    row = qkv + (size_t)s * QKV_N + hh * HD;
    wgt = qw;
    outp = q_bf + ((size_t)s * NH + hh) * HD;
    scale = SCALE_Q;
  } else {
    row = qkv + (size_t)s * QKV_N + QSZ + (hh - NH) * HD;
    wgt = kw;
    outp = k_bf + ((size_t)s * NKV + (hh - NH)) * HD;
    scale = 1.0f;
  }
  float x1 = row[l], x2 = row[l + 64];
  float ss = x1 * x1 + x2 * x2;
#pragma unroll
  for (int off = 32; off; off >>= 1) ss += __shfl_xor(ss, off, 64);
  float rs = rsqrtf(ss * (1.0f / 128.0f) + 1e-6f);
  float n1 = x1 * rs * wgt[l], n2 = x2 * rs * wgt[l + 64];
  float ang = (float)positions[s] * exp2f((float)l * (-LOG2_THETA / 64.0f));
  float sn, cs;
  sincosf(ang, &sn, &cs);
  outp[l]      = (__bf16)((n1 * cs - n2 * sn) * scale);
  outp[l + 64] = (__bf16)((n2 * cs + n1 * sn) * scale);
}

// ---------------- V transpose: qkv f32 -> vt_bf[hk][d][s] ----------------
__global__ __launch_bounds__(256) void v_prep(const float* __restrict__ qkv, __bf16* __restrict__ vt) {
  const int s0 = blockIdx.x * 32, hk = blockIdx.y;
  __shared__ float lv[32][129];
  const int t = threadIdx.x;
  {
    const int s = t >> 3, dseg = (t & 7) * 16;
    const float* src = qkv + (size_t)(s0 + s) * QKV_N + (QSZ + KVSZ) + hk * HD + dseg;
#pragma unroll
    for (int j = 0; j < 4; ++j) {
      float4 v = *(const float4*)(src + j * 4);
      lv[s][dseg + j * 4 + 0] = v.x;
      lv[s][dseg + j * 4 + 1] = v.y;
      lv[s][dseg + j * 4 + 2] = v.z;
      lv[s][dseg + j * 4 + 3] = v.w;
    }
  }
  __syncthreads();
  {
    const int d = t >> 1, sh = (t & 1) * 16;
    bf16x8 a, b;
#pragma unroll
    for (int j = 0; j < 8; ++j) {
      a[j] = (__bf16)lv[sh + j][d];
      b[j] = (__bf16)lv[sh + 8 + j][d];
    }
    __bf16* dst = vt + ((size_t)hk * HD + d) * S_LEN + s0 + sh;
    *(bf16x8*)dst = a;
    *(bf16x8*)(dst + 8) = b;
  }
}

// ---------------- flash attention: swapped QK^T + register double-buffer prefetch ----
// grid (32 qtiles reversed, 32 heads), 256 threads = 4 independent waves, 16 q-rows each.
// No launch_bounds cap: needs ~200 VGPRs so all 16 next-tile loads stay in flight.
__global__ __launch_bounds__(256) void flash_attn(
    const __bf16* __restrict__ q_bf, const __bf16* __restrict__ k_bf,
    const __bf16* __restrict__ vt_bf, __bf16* __restrict__ o_bf) {
  const int t = threadIdx.x;
  const int w = t >> 6, l = t & 63;
  const int qtile = gridDim.x - 1 - blockIdx.x;  // big blocks first (causal imbalance)
  const int h = blockIdx.y;
  const int hk = h >> 2;
  const int q0 = qtile * 64 + w * 16;
  const int lg = l >> 4, li = l & 15;

  __shared__ __attribute__((aligned(16))) __bf16 p_lds[4][16][40];

  // Q fragments (B-operand: lane holds Q[q=li][d=lg*8+j]), SCALE pre-folded in q_bf
  bf16x8 bq[4];
  {
    const __bf16* qp = q_bf + ((size_t)(q0 + li) * NH + h) * HD + lg * 8;
#pragma unroll
    for (int c = 0; c < 4; ++c) bq[c] = *(const bf16x8*)(qp + c * 32);
  }

  float m_r = -1e30f, l_r = 0.f;   // softmax state for q = q0 + li
  f32x4 o_acc[8];                  // o_acc[fd][r] = O[q=q0+lg*4+r][d=fd*16+li]
#pragma unroll
  for (int fd = 0; fd < 8; ++fd) o_acc[fd] = (f32x4){0.f, 0.f, 0.f, 0.f};

  const int nkt = ((q0 + 15) >> 5) + 1;

  const __bf16* kb0 = k_bf + (size_t)hk * HD + (size_t)li * KVSZ + lg * 8;
  const __bf16* vb0 = vt_bf + ((size_t)hk * HD + li) * S_LEN + lg * 8;

  auto LOADK = [&](int kbx, bf16x8* kr) {
    const __bf16* kp = kb0 + (size_t)kbx * 32 * KVSZ;
#pragma unroll
    for (int c = 0; c < 4; ++c) {
      kr[c]     = *(const bf16x8*)(kp + c * 32);
      kr[c + 4] = *(const bf16x8*)(kp + (size_t)16 * KVSZ + c * 32);
    }
  };
  auto LOADV = [&](int kbx, bf16x8* vr) {
    const __bf16* vp = vb0 + (size_t)kbx * 32;
#pragma unroll
    for (int fd = 0; fd < 8; ++fd)
      vr[fd] = *(const bf16x8*)(vp + (size_t)fd * 16 * S_LEN);
  };
  auto COMPUTE = [&](int kb, const bf16x8* kr, const bf16x8* vr) {
    f32x4 s0 = {0.f, 0.f, 0.f, 0.f}, s1 = {0.f, 0.f, 0.f, 0.f};
#pragma unroll
    for (int c = 0; c < 4; ++c) {
      s0 = __builtin_amdgcn_mfma_f32_16x16x32_bf16(kr[c],     bq[c], s0, 0, 0, 0);
      s1 = __builtin_amdgcn_mfma_f32_16x16x32_bf16(kr[c + 4], bq[c], s1, 0, 0, 0);
    }
    // lane holds S[key = kb*32 + lg*4 + r (+16)][q = q0+li]
    const int q = q0 + li;
    const int key0 = kb * 32 + lg * 4;
    float v0[4], v1[4];
#pragma unroll
    for (int r = 0; r < 4; ++r) {
      v0[r] = (key0 + r      <= q) ? s0[r] : -1e30f;
      v1[r] = (key0 + r + 16 <= q) ? s1[r] : -1e30f;
    }
    float tm = fmaxf(fmaxf(fmaxf(v0[0], v0[1]), fmaxf(v0[2], v0[3])),
                     fmaxf(fmaxf(v1[0], v1[1]), fmaxf(v1[2], v1[3])));
    tm = fmaxf(tm, __shfl_xor(tm, 16));
    tm = fmaxf(tm, __shfl_xor(tm, 32));
    float mn = fmaxf(m_r, tm);
    float sc = __expf(m_r - mn);
    float e0[4], e1[4], ps = 0.f;
#pragma unroll
    for (int r = 0; r < 4; ++r) {
      e0[r] = __expf(v0[r] - mn);
      e1[r] = __expf(v1[r] - mn);
      ps += e0[r] + e1[r];
    }
    ps += __shfl_xor(ps, 16);
    ps += __shfl_xor(ps, 32);
    l_r = l_r * sc + ps;
    m_r = mn;
#pragma unroll
    for (int r = 0; r < 4; ++r) {
      float scq = __shfl(sc, lg * 4 + r, 16);
#pragma unroll
      for (int fd = 0; fd < 8; ++fd) o_acc[fd][r] *= scq;
    }
    // P relayout via per-wave LDS roundtrip -> A-frag (row=q=li, key=lg*8+j)
    bf16x4 pw0, pw1;
#pragma unroll
    for (int r = 0; r < 4; ++r) { pw0[r] = (__bf16)e0[r]; pw1[r] = (__bf16)e1[r]; }
    *(bf16x4*)&p_lds[w][li][lg * 4]      = pw0;
    *(bf16x4*)&p_lds[w][li][lg * 4 + 16] = pw1;
    bf16x8 pa = *(const bf16x8*)&p_lds[w][li][lg * 8];
#pragma unroll
    for (int fd = 0; fd < 8; ++fd)
      o_acc[fd] = __builtin_amdgcn_mfma_f32_16x16x32_bf16(pa, vr[fd], o_acc[fd], 0, 0, 0);
  };

  bf16x8 k0[8], v0r[8], k1[8], v1r[8];
  LOADK(0, k0); LOADV(0, v0r);
  int kb = 0;
  while (true) {
    {  // compute k0/v0, prefetch into k1/v1
      int kbn = (kb + 1 < nkt) ? kb + 1 : kb;
      LOADK(kbn, k1); LOADV(kbn, v1r);
      COMPUTE(kb, k0, v0r);
      if (++kb >= nkt) break;
    }
    {  // compute k1/v1, prefetch into k0/v0
      int kbn = (kb + 1 < nkt) ? kb + 1 : kb;
      LOADK(kbn, k0); LOADV(kbn, v0r);
      COMPUTE(kb, k1, v1r);
      if (++kb >= nkt) break;
    }
  }

  // normalize + write o_bf[s][h*128+d]; l for q-row lg*4+r via shfl broadcast
  const size_t obase = (size_t)(q0 + lg * 4) * QSZ + (size_t)h * HD + li;
#pragma unroll
  for (int r = 0; r < 4; ++r) {
    float inv = 1.0f / __shfl(l_r, lg * 4 + r, 16);
#pragma unroll
    for (int fd = 0; fd < 8; ++fd)
      o_bf[obase + (size_t)r * QSZ + fd * 16] = (__bf16)(o_acc[fd][r] * inv);
  }
}

// ---------------- launch ----------------
extern "C" void kernel_launch(void* const* d_in, const int* in_sizes, int n_in,
                              void* d_out, int out_size, void* d_ws, size_t ws_size,
                              hipStream_t stream) {
  const int*   positions = (const int*)d_in[0];
  const float* hidden    = (const float*)d_in[1];
  const float* w_qkv     = (const float*)d_in[2];
  const float* w_o       = (const float*)d_in[3];
  const float* q_norm_w  = (const float*)d_in[4];
  const float* k_norm_w  = (const float*)d_in[5];
  float* out = (float*)d_out;

  char* p = (char*)d_ws;
  float*  qkv = (float*)p;   p += (size_t)S_LEN * QKV_N * 4;   // 50.3 MB
  __bf16* hs  = (__bf16*)p;  p += (size_t)S_LEN * HID * 2;     // 10.5 MB
  __bf16* wq  = (__bf16*)p;  p += (size_t)QKV_N * HID * 2;     // 31.5 MB
  __bf16* wo  = (__bf16*)p;  p += (size_t)HID * QSZ * 2;       // 21.0 MB
  __bf16* qb  = (__bf16*)p;  p += (size_t)S_LEN * QSZ * 2;     // 16.8 MB
  __bf16* kb  = (__bf16*)p;  p += (size_t)S_LEN * KVSZ * 2;    //  4.2 MB
  __bf16* vt  = (__bf16*)p;  p += (size_t)NKV * HD * S_LEN * 2;//  4.2 MB
  __bf16* ob  = (__bf16*)p;  p += (size_t)S_LEN * QSZ * 2;     // 16.8 MB

  castk<<<2048, 256, 0, stream>>>(hidden, hs, S_LEN * HID / 4);
  castk<<<2048, 256, 0, stream>>>(w_qkv, wq, QKV_N * HID / 4);
  castk<<<2048, 256, 0, stream>>>(w_o, wo, HID * QSZ / 4);

  gemm_bt<<<dim3(QKV_N / 128, S_LEN / 128), 256, 0, stream>>>(hs, wq, qkv, S_LEN, QKV_N, HID);

  norm_rope<<<dim3(S_LEN, NH + NKV), 64, 0, stream>>>(qkv, positions, q_norm_w, k_norm_w, qb, kb);
  v_prep<<<dim3(S_LEN / 32, NKV), 256, 0, stream>>>(qkv, vt);

  flash_attn<<<dim3(S_LEN / 64, NH), 256, 0, stream>>>(qb, kb, vt, ob);

  gemm_bt<<<dim3(HID / 128, S_LEN / 128), 256, 0, stream>>>(ob, wo, out, S_LEN, HID, QSZ);
}

// Round 5
// 432.618 us; speedup vs baseline: 1.8368x; 1.8368x over previous
//
#include <hip/hip_runtime.h>
#include <hip/hip_bf16.h>

typedef __bf16 bf16x8 __attribute__((ext_vector_type(8)));
typedef __bf16 bf16x4 __attribute__((ext_vector_type(4)));
typedef float f32x4 __attribute__((ext_vector_type(4)));

#define S_LEN 2048
#define HID 2560
#define NH 32
#define NKV 8
#define HD 128
#define QSZ 4096      // NH*HD
#define KVSZ 1024     // NKV*HD
#define QKV_N 6144    // QSZ + 2*KVSZ
#define SCALE_Q 0.08838834764831845f  // 128^-0.5
#define LOG2_THETA 13.287712379549449f // log2(10000)

// ---------------- f32 -> bf16 cast ----------------
__global__ void castk(const float* __restrict__ in, __bf16* __restrict__ out, int n4) {
  int i = blockIdx.x * blockDim.x + threadIdx.x;
  int stride = gridDim.x * blockDim.x;
  for (; i < n4; i += stride) {
    float4 v = ((const float4*)in)[i];
    bf16x4 o;
    o[0] = (__bf16)v.x; o[1] = (__bf16)v.y; o[2] = (__bf16)v.z; o[3] = (__bf16)v.w;
    ((bf16x4*)out)[i] = o;
  }
}

// ---------------- async global->LDS helper ----------------
__device__ __forceinline__ void gload16(const void* g, void* l) {
  __builtin_amdgcn_global_load_lds((const __attribute__((address_space(1))) void*)g,
                                   (__attribute__((address_space(3))) void*)l, 16, 0, 0);
}

// ---------------- bf16 GEMM: C[M][N] = A[M][K] * B[N][K]^T, fp32 out ----------------
__global__ __launch_bounds__(256, 2) void gemm_bt(
    const __bf16* __restrict__ A, const __bf16* __restrict__ B, float* __restrict__ C,
    int M, int N, int K) {
  __shared__ __attribute__((aligned(16))) __bf16 lta[128 * 32];
  __shared__ __attribute__((aligned(16))) __bf16 ltb[128 * 32];
  const int t = threadIdx.x, w = t >> 6, l = t & 63;
  const int bn = blockIdx.x, bm = blockIdx.y;
  const int wr = w >> 1, wc = w & 1;
  const int lg = l >> 4, li = l & 15;

  f32x4 acc[4][4];
#pragma unroll
  for (int i = 0; i < 4; ++i)
#pragma unroll
    for (int j = 0; j < 4; ++j) acc[i][j] = (f32x4){0.f, 0.f, 0.f, 0.f};

  const int nkt = K >> 5;
  const int c0 = w * 2, c1 = w * 2 + 1;
  const int row0 = c0 * 16 + (l >> 2), row1 = c1 * 16 + (l >> 2);
  const int cole = (l & 3) * 8;
  const __bf16* ga = A + (size_t)(bm * 128) * K + cole;
  const __bf16* gb = B + (size_t)(bn * 128) * K + cole;

  for (int kt = 0; kt < nkt; ++kt) {
    const size_t ko = (size_t)kt * 32;
    gload16(ga + (size_t)row0 * K + ko, &lta[c0 * 512]);
    gload16(gb + (size_t)row0 * K + ko, &ltb[c0 * 512]);
    gload16(ga + (size_t)row1 * K + ko, &lta[c1 * 512]);
    gload16(gb + (size_t)row1 * K + ko, &ltb[c1 * 512]);
    __syncthreads();
    bf16x8 af[4], bfr[4];
#pragma unroll
    for (int f = 0; f < 4; ++f) {
      af[f]  = *(const bf16x8*)&lta[(wr * 64 + f * 16 + li) * 32 + lg * 8];
      bfr[f] = *(const bf16x8*)&ltb[(wc * 64 + f * 16 + li) * 32 + lg * 8];
    }
#pragma unroll
    for (int fm = 0; fm < 4; ++fm)
#pragma unroll
      for (int fn = 0; fn < 4; ++fn)
        acc[fm][fn] = __builtin_amdgcn_mfma_f32_16x16x32_bf16(af[fm], bfr[fn], acc[fm][fn], 0, 0, 0);
    __syncthreads();
  }

  float* cp = C + (size_t)(bm * 128 + wr * 64 + lg * 4) * N + bn * 128 + wc * 64 + li;
#pragma unroll
  for (int fm = 0; fm < 4; ++fm)
#pragma unroll
    for (int fn = 0; fn < 4; ++fn)
#pragma unroll
      for (int r = 0; r < 4; ++r)
        cp[(size_t)(fm * 16 + r) * N + fn * 16] = acc[fm][fn][r];
}

// ---------------- fused RMSNorm + RoPE, write bf16 q/k ----------------
__global__ __launch_bounds__(64) void norm_rope(
    const float* __restrict__ qkv, const int* __restrict__ positions,
    const float* __restrict__ qw, const float* __restrict__ kw,
    __bf16* __restrict__ q_bf, __bf16* __restrict__ k_bf) {
  const int s = blockIdx.x, hh = blockIdx.y, l = threadIdx.x;
  const float* row;
  const float* wgt;
  __bf16* outp;
  float scale;
  if (hh < NH) {
    row = qkv + (size_t)s * QKV_N + hh * HD;
    wgt = qw;
    outp = q_bf + ((size_t)s * NH + hh) * HD;
    scale = SCALE_Q;
  } else {
    row = qkv + (size_t)s * QKV_N + QSZ + (hh - NH) * HD;
    wgt = kw;
    outp = k_bf + ((size_t)s * NKV + (hh - NH)) * HD;
    scale = 1.0f;
  }
  float x1 = row[l], x2 = row[l + 64];
  float ss = x1 * x1 + x2 * x2;
#pragma unroll
  for (int off = 32; off; off >>= 1) ss += __shfl_xor(ss, off, 64);
  float rs = rsqrtf(ss * (1.0f / 128.0f) + 1e-6f);
  float n1 = x1 * rs * wgt[l], n2 = x2 * rs * wgt[l + 64];
  float ang = (float)positions[s] * exp2f((float)l * (-LOG2_THETA / 64.0f));
  float sn, cs;
  sincosf(ang, &sn, &cs);
  outp[l]      = (__bf16)((n1 * cs - n2 * sn) * scale);
  outp[l + 64] = (__bf16)((n2 * cs + n1 * sn) * scale);
}

// ---------------- V transpose: qkv f32 -> vt_bf[hk][d][s] ----------------
__global__ __launch_bounds__(256) void v_prep(const float* __restrict__ qkv, __bf16* __restrict__ vt) {
  const int s0 = blockIdx.x * 32, hk = blockIdx.y;
  __shared__ float lv[32][129];
  const int t = threadIdx.x;
  {
    const int s = t >> 3, dseg = (t & 7) * 16;
    const float* src = qkv + (size_t)(s0 + s) * QKV_N + (QSZ + KVSZ) + hk * HD + dseg;
#pragma unroll
    for (int j = 0; j < 4; ++j) {
      float4 v = *(const float4*)(src + j * 4);
      lv[s][dseg + j * 4 + 0] = v.x;
      lv[s][dseg + j * 4 + 1] = v.y;
      lv[s][dseg + j * 4 + 2] = v.z;
      lv[s][dseg + j * 4 + 3] = v.w;
    }
  }
  __syncthreads();
  {
    const int d = t >> 1, sh = (t & 1) * 16;
    bf16x8 a, b;
#pragma unroll
    for (int j = 0; j < 8; ++j) {
      a[j] = (__bf16)lv[sh + j][d];
      b[j] = (__bf16)lv[sh + 8 + j][d];
    }
    __bf16* dst = vt + ((size_t)hk * HD + d) * S_LEN + s0 + sh;
    *(bf16x8*)dst = a;
    *(bf16x8*)(dst + 8) = b;
  }
}

// ---------------- flash attention: LDS-staged K/V, KV-group-per-XCD swizzle ----------
// 1-D grid of 1024 blocks: hk = b&7 (-> all blocks of one KV group on one XCD, K+V
// working set 1MB << 4MB L2), h = hk*4 + (b>>3)&3, qtile = 31 - (b>>5).
// 256 threads = 4 waves, 16 q-rows each. K/V tiles (32 keys) staged in LDS via
// global_load_lds(16B), double-buffered; XOR source-swizzle on K (and V) so the
// swizzled ds_read_b128 fragments are bank-conflict-benign.
__global__ __launch_bounds__(256, 3) void flash_attn(
    const __bf16* __restrict__ q_bf, const __bf16* __restrict__ k_bf,
    const __bf16* __restrict__ vt_bf, __bf16* __restrict__ o_bf) {
  const int t = threadIdx.x;
  const int w = t >> 6, l = t & 63;
  const int b = blockIdx.x;
  const int hk = b & 7;
  const int rem = b >> 3;                 // 0..127
  const int h = hk * 4 + (rem & 3);
  const int qtile = 31 - (rem >> 2);      // big tiles first
  const int q0 = qtile * 64 + w * 16;
  const int lg = l >> 4, li = l & 15;

  __shared__ __attribute__((aligned(16))) __bf16 k_lds[2][32 * 128];
  __shared__ __attribute__((aligned(16))) __bf16 v_lds[2][128 * 32];
  __shared__ __attribute__((aligned(16))) __bf16 p_lds[4][16][40];

  // Q fragments (B-operand: lane holds Q[q=li][d=lg*8+j]), SCALE pre-folded in q_bf
  bf16x8 bq[4];
  {
    const __bf16* qp = q_bf + ((size_t)(q0 + li) * NH + h) * HD + lg * 8;
#pragma unroll
    for (int c = 0; c < 4; ++c) bq[c] = *(const bf16x8*)(qp + c * 32);
  }

  float m_r = -1e30f, l_r = 0.f;   // softmax state for q = q0 + li
  f32x4 o_acc[8];                  // o_acc[fd][r] = O[q=q0+lg*4+r][d=fd*16+li]
#pragma unroll
  for (int fd = 0; fd < 8; ++fd) o_acc[fd] = (f32x4){0.f, 0.f, 0.f, 0.f};

  const int nkt = 2 * qtile + 2;   // shared by all 4 waves (covers q0+15 for w=3)

  // stage K tile [32 keys][128 d] and V^T tile [128 d][32 keys] for tile kb into buf.
  // LDS dest is linear (lane*16B); source global address carries the XOR swizzle
  // (both-sides-or-neither rule): K chunk' = chunk ^ (key&7), V chunk' = chunk ^ (d&3).
  auto STAGE = [&](int buf, int kb) {
#pragma unroll
    for (int j = 0; j < 2; ++j) {
      const int key = (t >> 4) + j * 16;                  // 0..31
      const int csrc = (t & 15) ^ (key & 7);              // 16B chunk within 256B row
      gload16(k_bf + (size_t)(kb * 32 + key) * KVSZ + hk * HD + csrc * 8,
              &k_lds[buf][j * 2048 + w * 512]);
    }
#pragma unroll
    for (int j = 0; j < 2; ++j) {
      const int d = (t >> 2) + j * 64;                    // 0..127
      const int csrc = (t & 3) ^ (d & 3);                 // 16B chunk within 64B row
      gload16(vt_bf + ((size_t)hk * HD + d) * S_LEN + kb * 32 + csrc * 8,
              &v_lds[buf][j * 2048 + w * 512]);
    }
  };

  STAGE(0, 0);
  for (int kb = 0; kb < nkt; ++kb) {
    __syncthreads();                       // stage(kb) landed (vmcnt drain + barrier)
    if (kb + 1 < nkt) STAGE((kb + 1) & 1, kb + 1);  // prefetch under compute
    const int cur = kb & 1;

    // K fragments from LDS (swizzled read): kr[c] row=li, kr[c+4] row=li+16
    bf16x8 kr[8];
#pragma unroll
    for (int c = 0; c < 4; ++c) {
      const int ch = ((c * 4 + lg) ^ (li & 7)) * 8;
      kr[c]     = *(const bf16x8*)&k_lds[cur][li * 128 + ch];
      kr[c + 4] = *(const bf16x8*)&k_lds[cur][(li + 16) * 128 + ch];
    }
    f32x4 s0 = {0.f, 0.f, 0.f, 0.f}, s1 = {0.f, 0.f, 0.f, 0.f};
#pragma unroll
    for (int c = 0; c < 4; ++c) {
      s0 = __builtin_amdgcn_mfma_f32_16x16x32_bf16(kr[c],     bq[c], s0, 0, 0, 0);
      s1 = __builtin_amdgcn_mfma_f32_16x16x32_bf16(kr[c + 4], bq[c], s1, 0, 0, 0);
    }
    // lane holds S[key = kb*32 + lg*4 + r (+16)][q = q0+li]
    const int q = q0 + li;
    const int key0 = kb * 32 + lg * 4;
    float v0[4], v1[4];
#pragma unroll
    for (int r = 0; r < 4; ++r) {
      v0[r] = (key0 + r      <= q) ? s0[r] : -1e30f;
      v1[r] = (key0 + r + 16 <= q) ? s1[r] : -1e30f;
    }
    float tm = fmaxf(fmaxf(fmaxf(v0[0], v0[1]), fmaxf(v0[2], v0[3])),
                     fmaxf(fmaxf(v1[0], v1[1]), fmaxf(v1[2], v1[3])));
    tm = fmaxf(tm, __shfl_xor(tm, 16));
    tm = fmaxf(tm, __shfl_xor(tm, 32));
    float mn = fmaxf(m_r, tm);
    float sc = __expf(m_r - mn);
    float e0[4], e1[4], ps = 0.f;
#pragma unroll
    for (int r = 0; r < 4; ++r) {
      e0[r] = __expf(v0[r] - mn);
      e1[r] = __expf(v1[r] - mn);
      ps += e0[r] + e1[r];
    }
    ps += __shfl_xor(ps, 16);
    ps += __shfl_xor(ps, 32);
    l_r = l_r * sc + ps;
    m_r = mn;
#pragma unroll
    for (int r = 0; r < 4; ++r) {
      float scq = __shfl(sc, lg * 4 + r, 16);
#pragma unroll
      for (int fd = 0; fd < 8; ++fd) o_acc[fd][r] *= scq;
    }
    // P relayout via per-wave LDS roundtrip -> A-frag (row=q=li, key=lg*8+j)
    bf16x4 pw0, pw1;
#pragma unroll
    for (int r = 0; r < 4; ++r) { pw0[r] = (__bf16)e0[r]; pw1[r] = (__bf16)e1[r]; }
    *(bf16x4*)&p_lds[w][li][lg * 4]      = pw0;
    *(bf16x4*)&p_lds[w][li][lg * 4 + 16] = pw1;
    bf16x8 pa = *(const bf16x8*)&p_lds[w][li][lg * 8];
    // PV: B fragments from swizzled V LDS (row=fd*16+li, chunk=lg^(li&3))
#pragma unroll
    for (int fd = 0; fd < 8; ++fd) {
      bf16x8 bv = *(const bf16x8*)&v_lds[cur][(fd * 16 + li) * 32 + ((lg ^ (li & 3)) * 8)];
      o_acc[fd] = __builtin_amdgcn_mfma_f32_16x16x32_bf16(pa, bv, o_acc[fd], 0, 0, 0);
    }
  }

  // normalize + write o_bf[s][h*128+d]; l for q-row lg*4+r via shfl broadcast
  const size_t obase = (size_t)(q0 + lg * 4) * QSZ + (size_t)h * HD + li;
#pragma unroll
  for (int r = 0; r < 4; ++r) {
    float inv = 1.0f / __shfl(l_r, lg * 4 + r, 16);
#pragma unroll
    for (int fd = 0; fd < 8; ++fd)
      o_bf[obase + (size_t)r * QSZ + fd * 16] = (__bf16)(o_acc[fd][r] * inv);
  }
}

// ---------------- launch ----------------
extern "C" void kernel_launch(void* const* d_in, const int* in_sizes, int n_in,
                              void* d_out, int out_size, void* d_ws, size_t ws_size,
                              hipStream_t stream) {
  const int*   positions = (const int*)d_in[0];
  const float* hidden    = (const float*)d_in[1];
  const float* w_qkv     = (const float*)d_in[2];
  const float* w_o       = (const float*)d_in[3];
  const float* q_norm_w  = (const float*)d_in[4];
  const float* k_norm_w  = (const float*)d_in[5];
  float* out = (float*)d_out;

  char* p = (char*)d_ws;
  float*  qkv = (float*)p;   p += (size_t)S_LEN * QKV_N * 4;   // 50.3 MB
  __bf16* hs  = (__bf16*)p;  p += (size_t)S_LEN * HID * 2;     // 10.5 MB
  __bf16* wq  = (__bf16*)p;  p += (size_t)QKV_N * HID * 2;     // 31.5 MB
  __bf16* wo  = (__bf16*)p;  p += (size_t)HID * QSZ * 2;       // 21.0 MB
  __bf16* qb  = (__bf16*)p;  p += (size_t)S_LEN * QSZ * 2;     // 16.8 MB
  __bf16* kb  = (__bf16*)p;  p += (size_t)S_LEN * KVSZ * 2;    //  4.2 MB
  __bf16* vt  = (__bf16*)p;  p += (size_t)NKV * HD * S_LEN * 2;//  4.2 MB
  __bf16* ob  = (__bf16*)p;  p += (size_t)S_LEN * QSZ * 2;     // 16.8 MB

  castk<<<2048, 256, 0, stream>>>(hidden, hs, S_LEN * HID / 4);
  castk<<<2048, 256, 0, stream>>>(w_qkv, wq, QKV_N * HID / 4);
  castk<<<2048, 256, 0, stream>>>(w_o, wo, HID * QSZ / 4);

  gemm_bt<<<dim3(QKV_N / 128, S_LEN / 128), 256, 0, stream>>>(hs, wq, qkv, S_LEN, QKV_N, HID);

  norm_rope<<<dim3(S_LEN, NH + NKV), 64, 0, stream>>>(qkv, positions, q_norm_w, k_norm_w, qb, kb);
  v_prep<<<dim3(S_LEN / 32, NKV), 256, 0, stream>>>(qkv, vt);

  flash_attn<<<1024, 256, 0, stream>>>(qb, kb, vt, ob);

  gemm_bt<<<dim3(HID / 128, S_LEN / 128), 256, 0, stream>>>(ob, wo, out, S_LEN, HID, QSZ);
}